// Round 14
// baseline (174.891 us; speedup 1.0000x reference)
//
#include <hip/hip_runtime.h>
#include <stdint.h>

// B=8, OBJ=128, INP=64, HID=256, D=192.
// R14: h stored FRAGMENT-MAJOR in LDS: frag(tj,kb)[lane] at
// (tj*16+kb)*512 + lane*8 shorts; element (j,k): tj=j>>5, kb=k>>4,
// lane = ((k>>3)&1)*32 + (j&31), e = k&7. bfr read = wave-uniform base +
// lane*16B = conflict-free 1KB ds_read_b128 (~8cyc vs ~12-18 for the old
// 32-row gather). R13 analysis: kernel was LDS-read-throughput-bound 3:1.

#define HID 256
#define NOBJ 128
#define NROW 1024   // B*OBJ

typedef __attribute__((ext_vector_type(8))) short short8;
typedef __attribute__((ext_vector_type(4))) float float4v;
typedef __attribute__((ext_vector_type(16))) float float16v;
typedef __attribute__((ext_vector_type(2))) unsigned int uint2v;
typedef __attribute__((ext_vector_type(4))) unsigned int uint4v;

__device__ __forceinline__ unsigned int f2bf_u(float f) {
    unsigned int u = __builtin_bit_cast(unsigned int, f);
    u += 0x7fffu + ((u >> 16) & 1u);   // RNE
    return u >> 16;
}
__device__ __forceinline__ unsigned int pack2(float a, float b) {
    return f2bf_u(a) | (f2bf_u(b) << 16);
}
__device__ __forceinline__ float relu(float v) { return v > 0.f ? v : 0.f; }

// LDS-only barrier: leaves global-load (vmcnt) prefetches in flight.
__device__ __forceinline__ void lds_barrier() {
    asm volatile("s_waitcnt lgkmcnt(0)\n\ts_barrier" ::: "memory");
}

// ---- setup: blocks [0,24) fragment-major weight pack: block = (layer m, n-tile tau).
//             blocks [24,536) encoder (2 rows each, fold b_enc into ea)
__global__ void setup_kernel(const float* __restrict__ x0, const float* __restrict__ x1,
                             const float* __restrict__ x2, const float* __restrict__ w_enc,
                             const float* __restrict__ b_enc,
                             const float* __restrict__ w1, const float* __restrict__ w2,
                             const float* __restrict__ w3,
                             unsigned short* __restrict__ wt,
                             float* __restrict__ ea, float* __restrict__ eb) {
    const int bx = blockIdx.x, t = threadIdx.x;
    __shared__ float lw[256][33];          // [k][n-within-tile]
    __shared__ float xs[2][192];
    if (bx < 24) {
        const int m = bx >> 3, tau = bx & 7;
        const float* w = (m == 0) ? w1 : (m == 1) ? w2 : w3;
        const int n = t & 31, kk = t >> 5;     // 8 k-rows per pass
#pragma unroll
        for (int rep = 0; rep < 32; ++rep) {
            int k = rep * 8 + kk;
            lw[k][n] = w[k * 256 + tau * 32 + n];   // coalesced 128B segments
        }
        __syncthreads();
        // pack: each (kb, lane) exactly once. lane = t&63, wave wq owns kb = wq*4..+3.
        unsigned short* outp = wt + (m * 8 + tau) * 8192;
        const int lane = t & 63, wq = t >> 6;
        const int h5 = lane >> 5, l31n = lane & 31;
#pragma unroll
        for (int rep = 0; rep < 4; ++rep) {
            const int kb = wq * 4 + rep;
            short8 v;
#pragma unroll
            for (int e = 0; e < 8; ++e)
                v[e] = (short)f2bf_u(lw[kb * 16 + h5 * 8 + e][l31n]);
            *(short8*)(outp + kb * 512 + lane * 8) = v;   // wave-contiguous 1KB
        }
        return;
    }
    const int e = bx - 24;                 // 512 groups x 2 rows
    for (int idx = t; idx < 384; idx += 256) {
        int r = idx / 192, d = idx % 192;
        int row = e * 2 + r;
        float v = (d < 64) ? x0[row * 64 + d]
                : (d < 128) ? x1[row * 64 + d - 64]
                : x2[row * 64 + d - 128];
        xs[r][d] = v;
    }
    __syncthreads();
    float aA[2] = {0.f, 0.f}, aB[2] = {0.f, 0.f};
#pragma unroll 16
    for (int d = 0; d < 192; ++d) {
        float wa = w_enc[d * 256 + t];
        float wb = w_enc[(192 + d) * 256 + t];
#pragma unroll
        for (int r = 0; r < 2; ++r) { aA[r] += xs[r][d] * wa; aB[r] += xs[r][d] * wb; }
    }
    float be = b_enc[t];
#pragma unroll
    for (int r = 0; r < 2; ++r) {
        ea[(e * 2 + r) * 256 + t] = aA[r] + be;
        eb[(e * 2 + r) * 256 + t] = aB[r];
    }
}

// ---- pair MLP + fused decoder: grid 1024, one WG per (b,i). 128 j-rows,
//      64 KB LDS h in FRAGMENT-MAJOR layout. Wave wv owns n-quarter n0=wv*64
//      as tn=2 x tj=4 tiles of 32x32x16. af = ring-4 (prefetch distance 3).
__global__ __launch_bounds__(256, 2) void pair_kernel(
        const float* __restrict__ ea, const float* __restrict__ eb,
        const unsigned short* __restrict__ wt,
        const float* __restrict__ b1, const float* __restrict__ b2,
        const float* __restrict__ b3,
        const float* __restrict__ wd1, const float* __restrict__ bd1,
        const float* __restrict__ wd2, const float* __restrict__ bd2,
        float* __restrict__ out) {
    __shared__ __align__(16) unsigned short hbuf[128 * 256];   // 64 KB, frag-major

    const int w = blockIdx.x, b = w >> 7;
    const int t = threadIdx.x, wv = t >> 6, lane = t & 63;
    const int l31 = lane & 31, h5 = lane >> 5;
    const int n0 = wv * 64;

    const unsigned short* aptr = wt + lane * 8;   // + ((l*8 + wv*2+tn)*16 + kb)*512

    short8 af[4][2], bfr[2][4];
    // flat A-pipeline: preload g=0,1,2 (layer 0, kb 0..2) before the preamble
#pragma unroll
    for (int pg = 0; pg < 3; ++pg) {
        af[pg][0] = *(const short8*)(aptr + ((wv * 2 + 0) * 16 + pg) * 512);
        af[pg][1] = *(const short8*)(aptr + ((wv * 2 + 1) * 16 + pg) * 512);
    }

    // preamble: h0[j][k] = relu(ea[w][k] + eb[b*128+j][k]) written FRAG-MAJOR.
    // Wave wv covers kb in [wv*4, wv*4+4); lane (l31,h5) owns row j=jl*32+l31,
    // k-chunk = kb*16 + h5*8. Write = wave-contiguous ds_write_b128.
    {
        const float* ebbase = eb + (b * NOBJ) * 256;
        const float* eap = ea + w * 256;
        float4v ael[4][2];
#pragma unroll
        for (int kbl = 0; kbl < 4; ++kbl) {
            const int k0 = (wv * 4 + kbl) * 16 + h5 * 8;
            ael[kbl][0] = *(const float4v*)(eap + k0);
            ael[kbl][1] = *(const float4v*)(eap + k0 + 4);
        }
#pragma unroll
        for (int jl = 0; jl < 4; ++jl) {
            const int j = jl * 32 + l31;
#pragma unroll
            for (int kbl = 0; kbl < 4; ++kbl) {
                const int kb = wv * 4 + kbl;
                const int k0 = kb * 16 + h5 * 8;
                float4v e0 = *(const float4v*)(ebbase + j * 256 + k0);
                float4v e1 = *(const float4v*)(ebbase + j * 256 + k0 + 4);
                uint4v v;
                v[0] = pack2(relu(ael[kbl][0][0] + e0[0]), relu(ael[kbl][0][1] + e0[1]));
                v[1] = pack2(relu(ael[kbl][0][2] + e0[2]), relu(ael[kbl][0][3] + e0[3]));
                v[2] = pack2(relu(ael[kbl][1][0] + e1[0]), relu(ael[kbl][1][1] + e1[1]));
                v[3] = pack2(relu(ael[kbl][1][2] + e1[2]), relu(ael[kbl][1][3] + e1[3]));
                *(uint4v*)(hbuf + (jl * 16 + kb) * 512 + lane * 8) = v;
            }
        }
    }
    lds_barrier();

    // bfr kb=0 of layer 0: conflict-free contiguous read
#pragma unroll
    for (int tj = 0; tj < 4; ++tj)
        bfr[0][tj] = *(const short8*)(hbuf + (tj * 16) * 512 + lane * 8);

    float16v acc[2][4];   // [tn][tj]

#pragma unroll
    for (int l = 0; l < 3; ++l) {
        const float* bias = (l == 0) ? b1 : (l == 1) ? b2 : b3;
        // acc init: reg r of tile tn -> n = n0+tn*32 + (r&3)+8*(r>>2)+4*h5
#pragma unroll
        for (int tn = 0; tn < 2; ++tn)
#pragma unroll
            for (int q = 0; q < 4; ++q) {
                float4v bv = *(const float4v*)(bias + n0 + tn * 32 + q * 8 + h5 * 4);
#pragma unroll
                for (int i = 0; i < 4; ++i)
#pragma unroll
                    for (int tj = 0; tj < 4; ++tj)
                        acc[tn][tj][q * 4 + i] = bv[i];
            }
#pragma unroll
        for (int kb = 0; kb < 16; ++kb) {
            const int g = l * 16 + kb, gp = g + 3;
            if (gp < 48) {   // prefetch 3 steps ahead (crosses layer boundaries)
                const int lp = gp >> 4, kp = gp & 15;
                af[gp & 3][0] = *(const short8*)(aptr + ((lp * 8 + wv * 2 + 0) * 16 + kp) * 512);
                af[gp & 3][1] = *(const short8*)(aptr + ((lp * 8 + wv * 2 + 1) * 16 + kp) * 512);
            }
            if (kb < 15) {   // prefetch next step's B from LDS (frag-major, conflict-free)
#pragma unroll
                for (int tj = 0; tj < 4; ++tj)
                    bfr[(kb + 1) & 1][tj] =
                        *(const short8*)(hbuf + (tj * 16 + kb + 1) * 512 + lane * 8);
            }
#pragma unroll
            for (int tn = 0; tn < 2; ++tn)
#pragma unroll
                for (int tj = 0; tj < 4; ++tj)
                    acc[tn][tj] = __builtin_amdgcn_mfma_f32_32x32x16_bf16(
                        af[g & 3][tn], bfr[kb & 1][tj], acc[tn][tj], 0, 0, 0);
        }
        lds_barrier();   // hbuf reads of layer l done; af prefetch stays in flight

        if (l < 2) {
            // writeback into frag-major: quad q of (tn,tj): next-layer k = nb_..nb_+3,
            // j = tj*32+l31. frag(tj, nb_>>4), lane' = ((nb_>>3)&1)*32 + l31, e = nb_&7.
#pragma unroll
            for (int tn = 0; tn < 2; ++tn)
#pragma unroll
                for (int q = 0; q < 4; ++q) {
                    const int nb_ = n0 + tn * 32 + 8 * q + 4 * h5;
                    const int kbf = nb_ >> 4;
                    const int halfsel = (nb_ >> 3) & 1;
                    const int sub = nb_ & 7;
#pragma unroll
                    for (int tj = 0; tj < 4; ++tj) {
                        int addr = (tj * 16 + kbf) * 512 + (halfsel * 32 + l31) * 8 + sub;
                        *(uint2v*)(hbuf + addr) = (uint2v){
                            pack2(relu(acc[tn][tj][q * 4]), relu(acc[tn][tj][q * 4 + 1])),
                            pack2(relu(acc[tn][tj][q * 4 + 2]), relu(acc[tn][tj][q * 4 + 3]))};
                    }
                }
            lds_barrier();
            // bfr kb=0 of next layer
#pragma unroll
            for (int tj = 0; tj < 4; ++tj)
                bfr[0][tj] = *(const short8*)(hbuf + (tj * 16) * 512 + lane * 8);
        }
    }

    // ---- fused epilogue: pooled (mean_j + b3) -> LDS, then decoder GEMVs.
    float* fs = (float*)hbuf;   // pm[0..256) | t1[256..512) | partial[512..768)
    {
#pragma unroll
        for (int tn = 0; tn < 2; ++tn)
#pragma unroll
            for (int r = 0; r < 16; ++r) {
                float s = acc[tn][0][r] + acc[tn][1][r] + acc[tn][2][r] + acc[tn][3][r];
                s += __shfl_xor(s, 1);
                s += __shfl_xor(s, 2);
                s += __shfl_xor(s, 4);
                s += __shfl_xor(s, 8);
                s += __shfl_xor(s, 16);
                if (l31 == 0) {
                    const int n = n0 + tn * 32 + (r & 3) + 8 * (r >> 2) + 4 * h5;
                    fs[n] = s * 0.0078125f;
                }
            }
    }
    __syncthreads();
    // stage 1: t1[t] = relu(pm . wd1[:,t] + bd1[t])
    {
        float a1 = bd1[t];
#pragma unroll 16
        for (int k = 0; k < 256; ++k) a1 += fs[k] * wd1[k * 256 + t];
        __syncthreads();
        fs[256 + t] = relu(a1);
    }
    __syncthreads();
    // stage 2: wave wv handles k in [wv*64, wv*64+64); lane = output o
    {
        const int o = lane;
        float p = 0.f;
        const float* w2p = wd2 + (wv * 64) * 64 + o;
#pragma unroll 16
        for (int kk = 0; kk < 64; ++kk) p += fs[256 + wv * 64 + kk] * w2p[kk * 64];
        fs[512 + wv * 64 + o] = p;
    }
    __syncthreads();
    if (t < 64)
        out[w * 64 + t] = fs[512 + t] + fs[576 + t] + fs[640 + t] + fs[704 + t] + bd2[t];
}

extern "C" void kernel_launch(void* const* d_in, const int* in_sizes, int n_in,
                              void* d_out, int out_size, void* d_ws, size_t ws_size,
                              hipStream_t stream) {
    const float* x0    = (const float*)d_in[0];
    const float* x1    = (const float*)d_in[1];
    const float* x2    = (const float*)d_in[2];
    const float* w_enc = (const float*)d_in[3];
    const float* b_enc = (const float*)d_in[4];
    const float* w1    = (const float*)d_in[5];
    const float* b1    = (const float*)d_in[6];
    const float* w2    = (const float*)d_in[7];
    const float* b2    = (const float*)d_in[8];
    const float* w3    = (const float*)d_in[9];
    const float* b3    = (const float*)d_in[10];
    const float* wd1   = (const float*)d_in[11];
    const float* bd1   = (const float*)d_in[12];
    const float* wd2   = (const float*)d_in[13];
    const float* bd2   = (const float*)d_in[14];
    float* out = (float*)d_out;

    // workspace: wfrag (384KB) | ea (1MB) | eb (1MB)
    unsigned short* wt = (unsigned short*)d_ws;
    float* ea = (float*)((char*)d_ws + 3 * 65536 * sizeof(unsigned short));
    float* eb = ea + NROW * HID;

    setup_kernel<<<536, 256, 0, stream>>>(x0, x1, x2, w_enc, b_enc, w1, w2, w3, wt, ea, eb);
    pair_kernel<<<NROW, 256, 0, stream>>>(ea, eb, wt, b1, b2, b3,
                                          wd1, bd1, wd2, bd2, out);
}

// Round 15
// 167.602 us; speedup vs baseline: 1.0435x; 1.0435x over previous
//
#include <hip/hip_runtime.h>
#include <stdint.h>

// B=8, OBJ=128, INP=64, HID=256, D=192.
// R15 = R12's pair core (best measured: 70.1us — ring-2 af distance-1,
// row-major swizzled hbuf, coalesced preamble) + R13's fused decoder
// epilogue (saves ~25-35us of kernel-boundary overhead). R13's ring-4 and
// R14's frag-major LDS were both measured regressions and are reverted.

#define HID 256
#define NOBJ 128
#define NROW 1024   // B*OBJ

typedef __attribute__((ext_vector_type(8))) short short8;
typedef __attribute__((ext_vector_type(4))) float float4v;
typedef __attribute__((ext_vector_type(16))) float float16v;
typedef __attribute__((ext_vector_type(2))) unsigned int uint2v;

__device__ __forceinline__ unsigned int f2bf_u(float f) {
    unsigned int u = __builtin_bit_cast(unsigned int, f);
    u += 0x7fffu + ((u >> 16) & 1u);   // RNE
    return u >> 16;
}
__device__ __forceinline__ unsigned int pack2(float a, float b) {
    return f2bf_u(a) | (f2bf_u(b) << 16);
}
__device__ __forceinline__ float relu(float v) { return v > 0.f ? v : 0.f; }

// LDS-only barrier: leaves global-load (vmcnt) prefetches in flight.
__device__ __forceinline__ void lds_barrier() {
    asm volatile("s_waitcnt lgkmcnt(0)\n\ts_barrier" ::: "memory");
}

// ---- setup: blocks [0,24) fragment-major weight pack: block = (layer m, n-tile tau).
//             blocks [24,536) encoder (2 rows each, fold b_enc into ea)
__global__ void setup_kernel(const float* __restrict__ x0, const float* __restrict__ x1,
                             const float* __restrict__ x2, const float* __restrict__ w_enc,
                             const float* __restrict__ b_enc,
                             const float* __restrict__ w1, const float* __restrict__ w2,
                             const float* __restrict__ w3,
                             unsigned short* __restrict__ wt,
                             float* __restrict__ ea, float* __restrict__ eb) {
    const int bx = blockIdx.x, t = threadIdx.x;
    __shared__ float lw[256][33];          // [k][n-within-tile]
    __shared__ float xs[2][192];
    if (bx < 24) {
        const int m = bx >> 3, tau = bx & 7;
        const float* w = (m == 0) ? w1 : (m == 1) ? w2 : w3;
        const int n = t & 31, kk = t >> 5;     // 8 k-rows per pass
#pragma unroll
        for (int rep = 0; rep < 32; ++rep) {
            int k = rep * 8 + kk;
            lw[k][n] = w[k * 256 + tau * 32 + n];   // coalesced 128B segments
        }
        __syncthreads();
        // pack: each (kb, lane) exactly once. lane = t&63, wave wq owns kb = wq*4..+3.
        unsigned short* outp = wt + (m * 8 + tau) * 8192;
        const int lane = t & 63, wq = t >> 6;
        const int h5 = lane >> 5, l31n = lane & 31;
#pragma unroll
        for (int rep = 0; rep < 4; ++rep) {
            const int kb = wq * 4 + rep;
            short8 v;
#pragma unroll
            for (int e = 0; e < 8; ++e)
                v[e] = (short)f2bf_u(lw[kb * 16 + h5 * 8 + e][l31n]);
            *(short8*)(outp + kb * 512 + lane * 8) = v;   // wave-contiguous 1KB
        }
        return;
    }
    const int e = bx - 24;                 // 512 groups x 2 rows
    for (int idx = t; idx < 384; idx += 256) {
        int r = idx / 192, d = idx % 192;
        int row = e * 2 + r;
        float v = (d < 64) ? x0[row * 64 + d]
                : (d < 128) ? x1[row * 64 + d - 64]
                : x2[row * 64 + d - 128];
        xs[r][d] = v;
    }
    __syncthreads();
    float aA[2] = {0.f, 0.f}, aB[2] = {0.f, 0.f};
#pragma unroll 16
    for (int d = 0; d < 192; ++d) {
        float wa = w_enc[d * 256 + t];
        float wb = w_enc[(192 + d) * 256 + t];
#pragma unroll
        for (int r = 0; r < 2; ++r) { aA[r] += xs[r][d] * wa; aB[r] += xs[r][d] * wb; }
    }
    float be = b_enc[t];
#pragma unroll
    for (int r = 0; r < 2; ++r) {
        ea[(e * 2 + r) * 256 + t] = aA[r] + be;
        eb[(e * 2 + r) * 256 + t] = aB[r];
    }
}

// ---- pair MLP + fused decoder: grid 1024, one WG per (b,i). 128 j-rows,
//      64 KB LDS h, swizzle: elem(j,k) at j*256 + ((k>>3 ^ (j&31))<<3) + (k&7).
//      Wave wv owns n-quarter n0 = wv*64 as tn=2 x tj=4 tiles of 32x32x16.
//      af ring-2 (distance 1) — R12's measured-best config.
__global__ __launch_bounds__(256, 2) void pair_kernel(
        const float* __restrict__ ea, const float* __restrict__ eb,
        const unsigned short* __restrict__ wt,
        const float* __restrict__ b1, const float* __restrict__ b2,
        const float* __restrict__ b3,
        const float* __restrict__ wd1, const float* __restrict__ bd1,
        const float* __restrict__ wd2, const float* __restrict__ bd2,
        float* __restrict__ out) {
    __shared__ __align__(16) unsigned short hbuf[128 * 256];   // 64 KB

    const int w = blockIdx.x, b = w >> 7;
    const int t = threadIdx.x, wv = t >> 6, lane = t & 63;
    const int l31 = lane & 31, h5 = lane >> 5;
    const int n0 = wv * 64;

    const unsigned short* aptr = wt + lane * 8;   // + ((l*8 + wv*2+tn)*16 + kb)*512

    short8 af[2][2], bfr[2][4];
    // flat A-pipeline: layer0/kb0 issued before the preamble
    af[0][0] = *(const short8*)(aptr + ((wv * 2 + 0) * 16) * 512);
    af[0][1] = *(const short8*)(aptr + ((wv * 2 + 1) * 16) * 512);

    // preamble: h0[j][k] = relu(ea[w][k] + eb[b*128+j][k]); wave fills j=wv*32..+31
    {
        const float4v va = *(const float4v*)(ea + w * 256 + lane * 4);
        const float* ebbase = eb + (b * NOBJ) * 256;
        const int c = lane >> 1, sub = (lane & 1) * 4;
#pragma unroll 4
        for (int jj = 0; jj < 32; ++jj) {
            const int j = wv * 32 + jj;
            float4v vb = *(const float4v*)(ebbase + j * 256 + lane * 4);
            int addr = j * 256 + ((c ^ (j & 31)) << 3) + sub;
            *(uint2v*)(hbuf + addr) = (uint2v){
                pack2(relu(va[0] + vb[0]), relu(va[1] + vb[1])),
                pack2(relu(va[2] + vb[2]), relu(va[3] + vb[3]))};
        }
    }
    lds_barrier();

    int jb[4];
#pragma unroll
    for (int tj = 0; tj < 4; ++tj) jb[tj] = (tj * 32 + l31) * 256;
    // bfr kb=0 of layer 0: k-chunk ck = h5
#pragma unroll
    for (int tj = 0; tj < 4; ++tj)
        bfr[0][tj] = *(const short8*)(hbuf + jb[tj] + ((h5 ^ l31) << 3));

    float16v acc[2][4];   // [tn][tj]

#pragma unroll
    for (int l = 0; l < 3; ++l) {
        const float* bias = (l == 0) ? b1 : (l == 1) ? b2 : b3;
        // acc init: reg r of tile tn -> n = n0+tn*32 + (r&3)+8*(r>>2)+4*h5
#pragma unroll
        for (int tn = 0; tn < 2; ++tn)
#pragma unroll
            for (int q = 0; q < 4; ++q) {
                float4v bv = *(const float4v*)(bias + n0 + tn * 32 + q * 8 + h5 * 4);
#pragma unroll
                for (int i = 0; i < 4; ++i)
#pragma unroll
                    for (int tj = 0; tj < 4; ++tj)
                        acc[tn][tj][q * 4 + i] = bv[i];
            }
#pragma unroll
        for (int kb = 0; kb < 16; ++kb) {
            const int g = l * 16 + kb, gp = g + 1;
            if (gp < 48) {   // prefetch next step's A (crosses layer boundaries)
                const int lp = gp >> 4, kp = gp & 15;
                af[gp & 1][0] = *(const short8*)(aptr + ((lp * 8 + wv * 2 + 0) * 16 + kp) * 512);
                af[gp & 1][1] = *(const short8*)(aptr + ((lp * 8 + wv * 2 + 1) * 16 + kp) * 512);
            }
            if (kb < 15) {   // prefetch next step's B from LDS (k-chunk ck=(kb+1)*2+h5)
                const int off = ((((kb + 1) * 2 + h5) ^ l31) << 3);
#pragma unroll
                for (int tj = 0; tj < 4; ++tj)
                    bfr[(kb + 1) & 1][tj] = *(const short8*)(hbuf + jb[tj] + off);
            }
#pragma unroll
            for (int tn = 0; tn < 2; ++tn)
#pragma unroll
                for (int tj = 0; tj < 4; ++tj)
                    acc[tn][tj] = __builtin_amdgcn_mfma_f32_32x32x16_bf16(
                        af[g & 1][tn], bfr[kb & 1][tj], acc[tn][tj], 0, 0, 0);
        }
        lds_barrier();   // hbuf reads of layer l done; af prefetch stays in flight

        if (l < 2) {
            // writeback: quad q of tile (tn,tj): n_base = n0+tn*32+8q+4h5 (4 consecutive n),
            // j = tj*32 + l31; packed 8B into swizzled h layout.
#pragma unroll
            for (int tn = 0; tn < 2; ++tn)
#pragma unroll
                for (int q = 0; q < 4; ++q) {
                    const int nb_ = n0 + tn * 32 + 8 * q + 4 * h5;
                    const int cn = nb_ >> 3, sub = nb_ & 7;
#pragma unroll
                    for (int tj = 0; tj < 4; ++tj) {
                        const int j = tj * 32 + l31;
                        int addr = j * 256 + ((cn ^ l31) << 3) + sub;
                        *(uint2v*)(hbuf + addr) = (uint2v){
                            pack2(relu(acc[tn][tj][q * 4]), relu(acc[tn][tj][q * 4 + 1])),
                            pack2(relu(acc[tn][tj][q * 4 + 2]), relu(acc[tn][tj][q * 4 + 3]))};
                    }
                }
            lds_barrier();
            // bfr kb=0 of next layer
#pragma unroll
            for (int tj = 0; tj < 4; ++tj)
                bfr[0][tj] = *(const short8*)(hbuf + jb[tj] + ((h5 ^ l31) << 3));
        }
    }

    // ---- fused epilogue: pooled (mean_j + b3) -> LDS, then decoder GEMVs.
    float* fs = (float*)hbuf;   // pm[0..256) | t1[256..512) | partial[512..768)
    {
#pragma unroll
        for (int tn = 0; tn < 2; ++tn)
#pragma unroll
            for (int r = 0; r < 16; ++r) {
                float s = acc[tn][0][r] + acc[tn][1][r] + acc[tn][2][r] + acc[tn][3][r];
                s += __shfl_xor(s, 1);
                s += __shfl_xor(s, 2);
                s += __shfl_xor(s, 4);
                s += __shfl_xor(s, 8);
                s += __shfl_xor(s, 16);
                if (l31 == 0) {
                    const int n = n0 + tn * 32 + (r & 3) + 8 * (r >> 2) + 4 * h5;
                    fs[n] = s * 0.0078125f;
                }
            }
    }
    __syncthreads();
    // stage 1: t1[t] = relu(pm . wd1[:,t] + bd1[t])
    {
        float a1 = bd1[t];
#pragma unroll 16
        for (int k = 0; k < 256; ++k) a1 += fs[k] * wd1[k * 256 + t];
        __syncthreads();
        fs[256 + t] = relu(a1);
    }
    __syncthreads();
    // stage 2: wave wv handles k in [wv*64, wv*64+64); lane = output o
    {
        const int o = lane;
        float p = 0.f;
        const float* w2p = wd2 + (wv * 64) * 64 + o;
#pragma unroll 16
        for (int kk = 0; kk < 64; ++kk) p += fs[256 + wv * 64 + kk] * w2p[kk * 64];
        fs[512 + wv * 64 + o] = p;
    }
    __syncthreads();
    if (t < 64)
        out[w * 64 + t] = fs[512 + t] + fs[576 + t] + fs[640 + t] + fs[704 + t] + bd2[t];
}

extern "C" void kernel_launch(void* const* d_in, const int* in_sizes, int n_in,
                              void* d_out, int out_size, void* d_ws, size_t ws_size,
                              hipStream_t stream) {
    const float* x0    = (const float*)d_in[0];
    const float* x1    = (const float*)d_in[1];
    const float* x2    = (const float*)d_in[2];
    const float* w_enc = (const float*)d_in[3];
    const float* b_enc = (const float*)d_in[4];
    const float* w1    = (const float*)d_in[5];
    const float* b1    = (const float*)d_in[6];
    const float* w2    = (const float*)d_in[7];
    const float* b2    = (const float*)d_in[8];
    const float* w3    = (const float*)d_in[9];
    const float* b3    = (const float*)d_in[10];
    const float* wd1   = (const float*)d_in[11];
    const float* bd1   = (const float*)d_in[12];
    const float* wd2   = (const float*)d_in[13];
    const float* bd2   = (const float*)d_in[14];
    float* out = (float*)d_out;

    // workspace: wfrag (384KB) | ea (1MB) | eb (1MB)
    unsigned short* wt = (unsigned short*)d_ws;
    float* ea = (float*)((char*)d_ws + 3 * 65536 * sizeof(unsigned short));
    float* eb = ea + NROW * HID;

    setup_kernel<<<536, 256, 0, stream>>>(x0, x1, x2, w_enc, b_enc, w1, w2, w3, wt, ea, eb);
    pair_kernel<<<NROW, 256, 0, stream>>>(ea, eb, wt, b1, b2, b3,
                                          wd1, bd1, wd2, bd2, out);
}

// Round 16
// 154.261 us; speedup vs baseline: 1.1337x; 1.0865x over previous
//
#include <hip/hip_runtime.h>
#include <stdint.h>

// B=8, OBJ=128, INP=64, HID=256, D=192.
// R16 ALGEBRAIC RESTRUCTURE: fc3 is linear (no relu before mean), so
//   mean_j(h2 @ w3 + b3) = mean_j(h2) @ w3 + b3,
// and relu comes only after wd1, so w3 folds into wd1:
//   t1 = relu(m2 @ (w3@wd1) + (b3@wd1 + bd1)) = relu(m2 @ W34 + b34).
// => the entire 3rd MFMA layer (1/3 of all MFMA work) becomes a GEMV,
// one LDS writeback+barrier phase disappears, and h2 stays fp32 through
// the mean (less rounding). Pair core otherwise = R15 (ring-2 af,
// row-major swizzled hbuf). Epilogue GEMV1 uses 4-way k-split for ILP.

#define HID 256
#define NOBJ 128
#define NROW 1024   // B*OBJ

typedef __attribute__((ext_vector_type(8))) short short8;
typedef __attribute__((ext_vector_type(4))) float float4v;
typedef __attribute__((ext_vector_type(16))) float float16v;
typedef __attribute__((ext_vector_type(2))) unsigned int uint2v;

__device__ __forceinline__ unsigned int f2bf_u(float f) {
    unsigned int u = __builtin_bit_cast(unsigned int, f);
    u += 0x7fffu + ((u >> 16) & 1u);   // RNE
    return u >> 16;
}
__device__ __forceinline__ unsigned int pack2(float a, float b) {
    return f2bf_u(a) | (f2bf_u(b) << 16);
}
__device__ __forceinline__ float relu(float v) { return v > 0.f ? v : 0.f; }

// LDS-only barrier: leaves global-load (vmcnt) prefetches in flight.
__device__ __forceinline__ void lds_barrier() {
    asm volatile("s_waitcnt lgkmcnt(0)\n\ts_barrier" ::: "memory");
}

// ---- setup:
//  blocks [0,16): fragment-major pack of w1,w2 (layer m = bx>>3, n-tile tau = bx&7)
//  blocks [16,528): encoder, 2 rows each (fold b_enc into ea)
//  blocks [528,784): W34 row m = bx-528:  W34[m][o] = sum_k w3[m][k]*wd1[k][o]
//  block  784:       b34[o] = sum_k b3[k]*wd1[k][o] + bd1[o]
__global__ void setup_kernel(const float* __restrict__ x0, const float* __restrict__ x1,
                             const float* __restrict__ x2, const float* __restrict__ w_enc,
                             const float* __restrict__ b_enc,
                             const float* __restrict__ w1, const float* __restrict__ w2,
                             const float* __restrict__ w3, const float* __restrict__ b3,
                             const float* __restrict__ wd1, const float* __restrict__ bd1,
                             unsigned short* __restrict__ wt,
                             float* __restrict__ ea, float* __restrict__ eb,
                             float* __restrict__ W34, float* __restrict__ b34) {
    const int bx = blockIdx.x, t = threadIdx.x;
    __shared__ float lw[256][33];          // [k][n-within-tile]
    __shared__ float xs[2][192];
    if (bx < 16) {
        const int m = bx >> 3, tau = bx & 7;
        const float* w = (m == 0) ? w1 : w2;
        const int n = t & 31, kk = t >> 5;     // 8 k-rows per pass
#pragma unroll
        for (int rep = 0; rep < 32; ++rep) {
            int k = rep * 8 + kk;
            lw[k][n] = w[k * 256 + tau * 32 + n];   // coalesced 128B segments
        }
        __syncthreads();
        unsigned short* outp = wt + (m * 8 + tau) * 8192;
        const int lane = t & 63, wq = t >> 6;
        const int h5 = lane >> 5, l31n = lane & 31;
#pragma unroll
        for (int rep = 0; rep < 4; ++rep) {
            const int kb = wq * 4 + rep;
            short8 v;
#pragma unroll
            for (int e = 0; e < 8; ++e)
                v[e] = (short)f2bf_u(lw[kb * 16 + h5 * 8 + e][l31n]);
            *(short8*)(outp + kb * 512 + lane * 8) = v;   // wave-contiguous 1KB
        }
        return;
    }
    if (bx < 528) {
        const int e = bx - 16;                 // 512 groups x 2 rows
        for (int idx = t; idx < 384; idx += 256) {
            int r = idx / 192, d = idx % 192;
            int row = e * 2 + r;
            float v = (d < 64) ? x0[row * 64 + d]
                    : (d < 128) ? x1[row * 64 + d - 64]
                    : x2[row * 64 + d - 128];
            xs[r][d] = v;
        }
        __syncthreads();
        float aA[2] = {0.f, 0.f}, aB[2] = {0.f, 0.f};
#pragma unroll 16
        for (int d = 0; d < 192; ++d) {
            float wa = w_enc[d * 256 + t];
            float wb = w_enc[(192 + d) * 256 + t];
#pragma unroll
            for (int r = 0; r < 2; ++r) { aA[r] += xs[r][d] * wa; aB[r] += xs[r][d] * wb; }
        }
        float be = b_enc[t];
#pragma unroll
        for (int r = 0; r < 2; ++r) {
            ea[(e * 2 + r) * 256 + t] = aA[r] + be;
            eb[(e * 2 + r) * 256 + t] = aB[r];
        }
        return;
    }
    if (bx < 784) {
        const int m = bx - 528;
        float a = 0.f;
#pragma unroll 8
        for (int k = 0; k < 256; ++k) a += w3[m * 256 + k] * wd1[k * 256 + t];
        W34[m * 256 + t] = a;
        return;
    }
    {   // b34
        float a = bd1[t];
#pragma unroll 8
        for (int k = 0; k < 256; ++k) a += b3[k] * wd1[k * 256 + t];
        b34[t] = a;
    }
}

// ---- pair MLP (2 layers) + fused decoder: grid 1024, one WG per (b,i).
//      128 j-rows, 64 KB LDS h, swizzle: elem(j,k) at
//      j*256 + ((k>>3 ^ (j&31))<<3) + (k&7). Wave wv owns n-quarter n0=wv*64
//      as tn=2 x tj=4 tiles of 32x32x16. af ring-2 (distance 1).
__global__ __launch_bounds__(256, 2) void pair_kernel(
        const float* __restrict__ ea, const float* __restrict__ eb,
        const unsigned short* __restrict__ wt,
        const float* __restrict__ b1, const float* __restrict__ b2,
        const float* __restrict__ W34, const float* __restrict__ b34,
        const float* __restrict__ wd2, const float* __restrict__ bd2,
        float* __restrict__ out) {
    __shared__ __align__(16) unsigned short hbuf[128 * 256];   // 64 KB

    const int w = blockIdx.x, b = w >> 7;
    const int t = threadIdx.x, wv = t >> 6, lane = t & 63;
    const int l31 = lane & 31, h5 = lane >> 5;
    const int n0 = wv * 64;

    const unsigned short* aptr = wt + lane * 8;   // + ((l*8 + wv*2+tn)*16 + kb)*512

    short8 af[2][2], bfr[2][4];
    af[0][0] = *(const short8*)(aptr + ((wv * 2 + 0) * 16) * 512);
    af[0][1] = *(const short8*)(aptr + ((wv * 2 + 1) * 16) * 512);

    // preamble: h0[j][k] = relu(ea[w][k] + eb[b*128+j][k]); wave fills j=wv*32..+31
    {
        const float4v va = *(const float4v*)(ea + w * 256 + lane * 4);
        const float* ebbase = eb + (b * NOBJ) * 256;
        const int c = lane >> 1, sub = (lane & 1) * 4;
#pragma unroll 4
        for (int jj = 0; jj < 32; ++jj) {
            const int j = wv * 32 + jj;
            float4v vb = *(const float4v*)(ebbase + j * 256 + lane * 4);
            int addr = j * 256 + ((c ^ (j & 31)) << 3) + sub;
            *(uint2v*)(hbuf + addr) = (uint2v){
                pack2(relu(va[0] + vb[0]), relu(va[1] + vb[1])),
                pack2(relu(va[2] + vb[2]), relu(va[3] + vb[3]))};
        }
    }
    lds_barrier();

    int jb[4];
#pragma unroll
    for (int tj = 0; tj < 4; ++tj) jb[tj] = (tj * 32 + l31) * 256;
#pragma unroll
    for (int tj = 0; tj < 4; ++tj)
        bfr[0][tj] = *(const short8*)(hbuf + jb[tj] + ((h5 ^ l31) << 3));

    float16v acc[2][4];   // [tn][tj]

#pragma unroll
    for (int l = 0; l < 2; ++l) {
        const float* bias = (l == 0) ? b1 : b2;
#pragma unroll
        for (int tn = 0; tn < 2; ++tn)
#pragma unroll
            for (int q = 0; q < 4; ++q) {
                float4v bv = *(const float4v*)(bias + n0 + tn * 32 + q * 8 + h5 * 4);
#pragma unroll
                for (int i = 0; i < 4; ++i)
#pragma unroll
                    for (int tj = 0; tj < 4; ++tj)
                        acc[tn][tj][q * 4 + i] = bv[i];
            }
#pragma unroll
        for (int kb = 0; kb < 16; ++kb) {
            const int g = l * 16 + kb, gp = g + 1;
            if (gp < 32) {   // prefetch next step's A (crosses the layer boundary)
                const int lp = gp >> 4, kp = gp & 15;
                af[gp & 1][0] = *(const short8*)(aptr + ((lp * 8 + wv * 2 + 0) * 16 + kp) * 512);
                af[gp & 1][1] = *(const short8*)(aptr + ((lp * 8 + wv * 2 + 1) * 16 + kp) * 512);
            }
            if (kb < 15) {   // prefetch next step's B from LDS
                const int off = ((((kb + 1) * 2 + h5) ^ l31) << 3);
#pragma unroll
                for (int tj = 0; tj < 4; ++tj)
                    bfr[(kb + 1) & 1][tj] = *(const short8*)(hbuf + jb[tj] + off);
            }
#pragma unroll
            for (int tn = 0; tn < 2; ++tn)
#pragma unroll
                for (int tj = 0; tj < 4; ++tj)
                    acc[tn][tj] = __builtin_amdgcn_mfma_f32_32x32x16_bf16(
                        af[g & 1][tn], bfr[kb & 1][tj], acc[tn][tj], 0, 0, 0);
        }
        lds_barrier();   // hbuf reads of layer l done

        if (l == 0) {
            // writeback h1 (relu, bf16) into swizzled layout
#pragma unroll
            for (int tn = 0; tn < 2; ++tn)
#pragma unroll
                for (int q = 0; q < 4; ++q) {
                    const int nb_ = n0 + tn * 32 + 8 * q + 4 * h5;
                    const int cn = nb_ >> 3, sub = nb_ & 7;
#pragma unroll
                    for (int tj = 0; tj < 4; ++tj) {
                        const int j = tj * 32 + l31;
                        int addr = j * 256 + ((cn ^ l31) << 3) + sub;
                        *(uint2v*)(hbuf + addr) = (uint2v){
                            pack2(relu(acc[tn][tj][q * 4]), relu(acc[tn][tj][q * 4 + 1])),
                            pack2(relu(acc[tn][tj][q * 4 + 2]), relu(acc[tn][tj][q * 4 + 3]))};
                    }
                }
            lds_barrier();
#pragma unroll
            for (int tj = 0; tj < 4; ++tj)
                bfr[0][tj] = *(const short8*)(hbuf + jb[tj] + ((h5 ^ l31) << 3));
        }
    }

    // ---- epilogue: m2 = mean_j(relu(h2)) -- NO: h2 has relu applied? NOTE:
    // reference: h2 = relu(...@w2+b2) (acc holds pre-relu). Apply relu here,
    // then m2 = mean_j relu(acc). Then t1 = relu(m2@W34 + b34); out = t1@wd2+bd2.
    float* fs = (float*)hbuf;   // m2[0..256) | p1[256..1280) | t1[1280..1536) | p2[1536..1792)
    {
#pragma unroll
        for (int tn = 0; tn < 2; ++tn)
#pragma unroll
            for (int r = 0; r < 16; ++r) {
                float s = relu(acc[tn][0][r]) + relu(acc[tn][1][r])
                        + relu(acc[tn][2][r]) + relu(acc[tn][3][r]);
                s += __shfl_xor(s, 1);
                s += __shfl_xor(s, 2);
                s += __shfl_xor(s, 4);
                s += __shfl_xor(s, 8);
                s += __shfl_xor(s, 16);
                if (l31 == 0) {
                    const int n = n0 + tn * 32 + (r & 3) + 8 * (r >> 2) + 4 * h5;
                    fs[n] = s * 0.0078125f;
                }
            }
    }
    __syncthreads();
    // stage 1: m2 @ W34 with 4-way k-split (wave wv covers k in [wv*64, wv*64+64))
    {
        float p0 = 0.f, p1 = 0.f, p2 = 0.f, p3 = 0.f;
        const float* wp = W34 + (wv * 64) * 256 + lane;
#pragma unroll 8
        for (int kk = 0; kk < 64; ++kk) {
            float mv = fs[wv * 64 + kk];
            p0 += mv * wp[kk * 256];
            p1 += mv * wp[kk * 256 + 64];
            p2 += mv * wp[kk * 256 + 128];
            p3 += mv * wp[kk * 256 + 192];
        }
        fs[256 + wv * 256 + lane]       = p0;
        fs[256 + wv * 256 + 64 + lane]  = p1;
        fs[256 + wv * 256 + 128 + lane] = p2;
        fs[256 + wv * 256 + 192 + lane] = p3;
    }
    __syncthreads();
    fs[1280 + t] = relu(fs[256 + t] + fs[512 + t] + fs[768 + t] + fs[1024 + t] + b34[t]);
    __syncthreads();
    // stage 2: t1 @ wd2 (wave wv covers k in [wv*64, wv*64+64), lane = output o)
    {
        float p = 0.f;
        const float* w2p = wd2 + (wv * 64) * 64 + lane;
#pragma unroll 8
        for (int kk = 0; kk < 64; ++kk) p += fs[1280 + wv * 64 + kk] * w2p[kk * 64];
        fs[1536 + wv * 64 + lane] = p;
    }
    __syncthreads();
    if (t < 64)
        out[w * 64 + t] = fs[1536 + t] + fs[1600 + t] + fs[1664 + t] + fs[1728 + t] + bd2[t];
}

extern "C" void kernel_launch(void* const* d_in, const int* in_sizes, int n_in,
                              void* d_out, int out_size, void* d_ws, size_t ws_size,
                              hipStream_t stream) {
    const float* x0    = (const float*)d_in[0];
    const float* x1    = (const float*)d_in[1];
    const float* x2    = (const float*)d_in[2];
    const float* w_enc = (const float*)d_in[3];
    const float* b_enc = (const float*)d_in[4];
    const float* w1    = (const float*)d_in[5];
    const float* b1    = (const float*)d_in[6];
    const float* w2    = (const float*)d_in[7];
    const float* b2    = (const float*)d_in[8];
    const float* w3    = (const float*)d_in[9];
    const float* b3    = (const float*)d_in[10];
    const float* wd1   = (const float*)d_in[11];
    const float* bd1   = (const float*)d_in[12];
    const float* wd2   = (const float*)d_in[13];
    const float* bd2   = (const float*)d_in[14];
    float* out = (float*)d_out;

    // workspace: wfrag (384KB slot, 256KB used) | ea 1MB | eb 1MB | W34 256KB | b34 1KB
    unsigned short* wt = (unsigned short*)d_ws;
    float* ea  = (float*)((char*)d_ws + 3 * 65536 * sizeof(unsigned short));
    float* eb  = ea + NROW * HID;
    float* W34 = eb + NROW * HID;
    float* b34 = W34 + 256 * 256;

    setup_kernel<<<785, 256, 0, stream>>>(x0, x1, x2, w_enc, b_enc, w1, w2,
                                          w3, b3, wd1, bd1, wt, ea, eb, W34, b34);
    pair_kernel<<<NROW, 256, 0, stream>>>(ea, eb, wt, b1, b2, W34, b34, wd2, bd2, out);
}